// Round 9
// baseline (256.783 us; speedup 1.0000x reference)
//
#include <hip/hip_runtime.h>
#include <hip/hip_bf16.h>

// MultiLoRA forward, single persistent kernel with 2-tile read/write pipeline.
//   out[row,o] = sum_r (sum_i x[row,i]*B[a,r,i]) * A[a,o,r],  a = ids[row/2048]
// SCALING = 16/16 = 1. x->bf16 MFMA for Bx (R0-proven); P2 all-f32 (R5-proven).
//
// Ledger (kernel-only = dur_us - ~161 fixed harness cost):
//   R0 fused-lockstep 88.5 | R1-R3 split ~123 | R4 staged 105 | R5/R6 split 91
//   R7 attribution: read-phase 58 us (invariant over 5 designs: pattern- and
//   TLP-insensitive, ~2.3 TB/s), write-phase 31 us.
// Fact: R0's 88.5 = 58 + 31 — phases fully serialized chip-wide (all blocks
// co-resident, lockstep). The one unexploited lever: overlap the read and
// write STREAMS. This kernel: 256 persistent blocks (1/CU, 512 thr), each
// owns tiles {2b, 2b+1}. Pipeline: P1(t0) | [P2(t0) rows interleaved with
// P1(t1) load+mfma steps — P2 has no dependency on P1(t1) loads, so stores
// and loads are concurrently in flight] | P2(t1).
// P1 = R0's 16-step direct-load MFMA + 8-wave LDS reduce (known 58us-class).
// P2 = R5's fill-shaped writer: lane owns 4 contiguous cols, A in 64 VGPRs,
// one dwordx4 NT store per row (1 KB contiguous per wave instruction).
#define RANK   16
#define IN_F   4096
#define OUT_F  4096
#define NROWS  8192
#define NBLK   256

typedef __bf16 bf16x8  __attribute__((ext_vector_type(8)));
typedef float  floatx4 __attribute__((ext_vector_type(4)));

static __device__ __forceinline__ bf16x8 cvt8(floatx4 a, floatx4 b) {
    bf16x8 r;
    r[0] = (__bf16)a[0]; r[1] = (__bf16)a[1]; r[2] = (__bf16)a[2]; r[3] = (__bf16)a[3];
    r[4] = (__bf16)b[0]; r[5] = (__bf16)b[1]; r[6] = (__bf16)b[2]; r[7] = (__bf16)b[3];
    return r;
}

__global__ __launch_bounds__(512, 2) void
lora_pipe_kernel(const float* __restrict__ x, const float* __restrict__ Aw,
                 const float* __restrict__ Bw, const int* __restrict__ ids,
                 float* __restrict__ out)
{
    const int blk  = blockIdx.x;            // 0..255, persistent 1/CU
    const int row0 = (blk * 2)     * 16;    // tile t0
    const int row1 = (blk * 2 + 1) * 16;    // tile t1 (same batch: 32|2048)
    const int ad0  = ids[row0 >> 11];
    const int ad1  = ids[row1 >> 11];
    const int tid  = threadIdx.x;
    const int wave = tid >> 6;              // 0..7
    const int lane = tid & 63;
    const int m    = lane & 15;
    const int quad = lane >> 4;

    __shared__ float red[8][256];           // cross-wave P1 reduce
    __shared__ float bxs[2][256];           // f32 Bx tiles [row%16][r]

    const int koff = wave * 512 + quad * 8; // 8-wave K split
    const float* xp0 = x + (size_t)(row0 + m) * IN_F + koff;
    const float* xp1 = x + (size_t)(row1 + m) * IN_F + koff;
    const float* bp0 = Bw + (size_t)ad0 * (RANK * IN_F) + m * IN_F + koff;
    const float* bp1 = Bw + (size_t)ad1 * (RANK * IN_F) + m * IN_F + koff;

    // P2 column ownership: lane -> 4 contiguous cols; 512 thr x 4 = 2048/pass.
    const int cbase = wave * 256 + lane * 4;

    // P2 row emitter: out[rowb+rr, c0..c0+3] = dot16(bxs[buf][rr,:], a[...])
    floatx4 a[16];                          // a[j*4+q] = A[c0+j][q*4..q*4+3]
    auto p2row = [&](int buf, int rowb, int c0, int rr) {
        const float* bx = &bxs[buf][rr * 16];
        const floatx4 b0 = *reinterpret_cast<const floatx4*>(bx);
        const floatx4 b1 = *reinterpret_cast<const floatx4*>(bx + 4);
        const floatx4 b2 = *reinterpret_cast<const floatx4*>(bx + 8);
        const floatx4 b3 = *reinterpret_cast<const floatx4*>(bx + 12);
        floatx4 ov;
#pragma unroll
        for (int j = 0; j < 4; ++j) {
            const floatx4 a0 = a[j * 4 + 0], a1 = a[j * 4 + 1];
            const floatx4 a2 = a[j * 4 + 2], a3 = a[j * 4 + 3];
            ov[j] = a0[0]*b0[0] + a0[1]*b0[1] + a0[2]*b0[2] + a0[3]*b0[3]
                  + a1[0]*b1[0] + a1[1]*b1[1] + a1[2]*b1[2] + a1[3]*b1[3]
                  + a2[0]*b2[0] + a2[1]*b2[1] + a2[2]*b2[2] + a2[3]*b2[3]
                  + a3[0]*b3[0] + a3[1]*b3[1] + a3[2]*b3[2] + a3[3]*b3[3];
        }
        __builtin_nontemporal_store(
            ov, reinterpret_cast<floatx4*>(out + (size_t)(rowb + rr) * OUT_F + c0));
    };
    auto loadA = [&](int ad, int c0) {
        const float* ap = Aw + ((size_t)ad * OUT_F + c0) * RANK;
#pragma unroll
        for (int i = 0; i < 16; ++i)
            a[i] = *reinterpret_cast<const floatx4*>(ap + i * 4);
    };
    auto reduceTo = [&](int buf, floatx4 acc) {
#pragma unroll
        for (int j = 0; j < 4; ++j)
            red[wave][(quad * 4 + j) * 16 + m] = acc[j];
        __syncthreads();
        if (tid < 256) {                    // t = (row%16)*16 + r
            float s = ((red[0][tid] + red[1][tid]) + (red[2][tid] + red[3][tid]))
                    + ((red[4][tid] + red[5][tid]) + (red[6][tid] + red[7][tid]));
            bxs[buf][tid] = s;
        }
        __syncthreads();
    };

    // ---- P1(t0): 16-step direct-load MFMA (R0-proven) ----
    floatx4 acc = {0.f, 0.f, 0.f, 0.f};
#pragma unroll
    for (int s = 0; s < 16; ++s) {
        floatx4 xa = *reinterpret_cast<const floatx4*>(xp0 + s * 32);
        floatx4 xb = *reinterpret_cast<const floatx4*>(xp0 + s * 32 + 4);
        floatx4 ba = *reinterpret_cast<const floatx4*>(bp0 + s * 32);
        floatx4 bb = *reinterpret_cast<const floatx4*>(bp0 + s * 32 + 4);
        acc = __builtin_amdgcn_mfma_f32_16x16x32_bf16(
            cvt8(xa, xb), cvt8(ba, bb), acc, 0, 0, 0);
    }
    reduceTo(0, acc);

    // ---- Interleave: P2(t0) rows woven between P1(t1) load->mfma steps ----
    loadA(ad0, cbase);                      // pass-0 A regs for t0
    acc = (floatx4){0.f, 0.f, 0.f, 0.f};
#pragma unroll
    for (int s = 0; s < 16; ++s) {
        // P1(t1) step-s loads: no dependency on P2 below -> stay in flight
        floatx4 xa = *reinterpret_cast<const floatx4*>(xp1 + s * 32);
        floatx4 xb = *reinterpret_cast<const floatx4*>(xp1 + s * 32 + 4);
        floatx4 ba = *reinterpret_cast<const floatx4*>(bp1 + s * 32);
        floatx4 bb = *reinterpret_cast<const floatx4*>(bp1 + s * 32 + 4);
        if (s == 8) loadA(ad0, 2048 + cbase);   // pass-1 A regs
        const int pass = s >> 3;            // 0 | 1
        const int c0   = pass * 2048 + cbase;
        const int rr   = (2 * s) & 15;
        p2row(0, row0, c0, rr);             // VALU + LDS + NT store
        p2row(0, row0, c0, rr + 1);
        acc = __builtin_amdgcn_mfma_f32_16x16x32_bf16(
            cvt8(xa, xb), cvt8(ba, bb), acc, 0, 0, 0);
    }
    reduceTo(1, acc);

    // ---- P2(t1): 2 passes x 16 rows ----
    loadA(ad1, cbase);
#pragma unroll 4
    for (int rr = 0; rr < 16; ++rr) p2row(1, row1, cbase, rr);
    loadA(ad1, 2048 + cbase);
#pragma unroll 4
    for (int rr = 0; rr < 16; ++rr) p2row(1, row1, 2048 + cbase, rr);
}

extern "C" void kernel_launch(void* const* d_in, const int* in_sizes, int n_in,
                              void* d_out, int out_size, void* d_ws, size_t ws_size,
                              hipStream_t stream) {
    const float* x   = (const float*)d_in[0]; // [4, 2048, 4096] f32
    const float* Aw  = (const float*)d_in[1]; // [8, 4096, 16]   f32
    const float* Bw  = (const float*)d_in[2]; // [8, 16, 4096]   f32
    const int*   ids = (const int*)d_in[3];   // [4] int32
    float* out = (float*)d_out;               // [4, 2048, 4096] f32

    lora_pipe_kernel<<<dim3(NBLK), dim3(512), 0, stream>>>(x, Aw, Bw, ids, out);
}